// Round 2
// baseline (512.146 us; speedup 1.0000x reference)
//
#include <hip/hip_runtime.h>
#include <stdint.h>

// Problem constants (from reference setup_inputs): B,H,T,S,D
#define B_ 2
#define H_ 16
#define T_ 2048
#define S_ 2048
#define D_ 128

typedef float f32x4 __attribute__((ext_vector_type(4)));

// ---------------------------------------------------------------------------
// Kernel 0: clear the two amax slots (replaces hipMemsetAsync in the graph)
__global__ void init_kernel(unsigned* __restrict__ amax_bits) {
  if (threadIdx.x < 2) amax_bits[threadIdx.x] = 0u;
}

// ---------------------------------------------------------------------------
// Kernel 1: abs-max reduction (uint-bit atomicMax; valid since |x| >= 0)
__global__ void amax_kernel(const float* __restrict__ x, long n4,
                            unsigned* __restrict__ out) {
  const f32x4* x4 = (const f32x4*)x;
  long i      = (long)blockIdx.x * blockDim.x + threadIdx.x;
  long stride = (long)gridDim.x * blockDim.x;
  float m = 0.0f;
  for (; i < n4; i += stride) {
    f32x4 v = x4[i];
    m = fmaxf(m, fmaxf(fmaxf(fabsf(v[0]), fabsf(v[1])),
                       fmaxf(fabsf(v[2]), fabsf(v[3]))));
  }
  #pragma unroll
  for (int off = 32; off; off >>= 1) m = fmaxf(m, __shfl_xor(m, off, 64));
  if ((threadIdx.x & 63) == 0) atomicMax(out, __float_as_uint(m));
}

// ---------------------------------------------------------------------------
// HW e4m3fn quantization helpers (v_cvt_pk_fp8_f32 is RNE, OCP on gfx950).
// Clamp first: reference clips to +-448 before casting; also protects the
// amax element from rounding above 448.
__device__ __forceinline__ float clamp448(float y) {
  return fminf(fmaxf(y, -448.0f), 448.0f);
}

// pack 8 floats (already scaled+clamped) into 8 e4m3 bytes (one i64)
__device__ __forceinline__ long pack_fp8x8(const float* f) {
  int d0 = 0, d1 = 0;
  d0 = __builtin_amdgcn_cvt_pk_fp8_f32(f[0], f[1], d0, false);
  d0 = __builtin_amdgcn_cvt_pk_fp8_f32(f[2], f[3], d0, true);
  d1 = __builtin_amdgcn_cvt_pk_fp8_f32(f[4], f[5], d1, false);
  d1 = __builtin_amdgcn_cvt_pk_fp8_f32(f[6], f[7], d1, true);
  return (long)(((unsigned long long)(unsigned)d1 << 32) | (unsigned)d0);
}

// ---------------------------------------------------------------------------
// Kernel 2: quantize v to e4m3 bytes + transpose -> Vt[bh][d][s]  (8 MB total)
// grid: 32 bh * 64 s-chunks of 32; block 256 = 128 d * 2 s-halves of 16
__global__ void quantv_kernel(const float* __restrict__ v,
                              unsigned char* __restrict__ vt,
                              const unsigned* __restrict__ amax_bits) {
  float amax = fmaxf(__uint_as_float(amax_bits[1]), 1e-12f);
  float inv  = 448.0f / amax;
  int bid = blockIdx.x;
  int bh  = bid >> 6;
  int s0  = (bid & 63) * 32;
  int d   = threadIdx.x & 127;
  int h2  = threadIdx.x >> 7;          // 0,1
  const float*   vb  = v  + (size_t)bh * S_ * D_;
  unsigned char* vtb = vt + (size_t)bh * D_ * S_;
  unsigned dw[4];
  #pragma unroll
  for (int q = 0; q < 4; ++q) {
    float f[4];
    #pragma unroll
    for (int j = 0; j < 4; ++j)
      f[j] = clamp448(vb[(size_t)(s0 + h2 * 16 + q * 4 + j) * D_ + d] * inv);
    int w = 0;
    w = __builtin_amdgcn_cvt_pk_fp8_f32(f[0], f[1], w, false);
    w = __builtin_amdgcn_cvt_pk_fp8_f32(f[2], f[3], w, true);
    dw[q] = (unsigned)w;
  }
  *(uint4*)(vtb + (size_t)d * S_ + s0 + h2 * 16) = *(const uint4*)dw;
}

// ---------------------------------------------------------------------------
// Kernel 3: GEMM  C[t,d] = (sum_s Aq[t,s]*Vq[s,d]) * scale_a*scale_v
// 1024 blocks: (bh, t-tile of 64). 4 waves, 16 rows each, full D=128 width.
// No LDS, no barriers. A f32 streamed from HBM, quantized in-register via HW
// cvt; B = 8-B loads from L2-resident fp8 Vt. fp8 MFMA, f32 accumulate.
template <bool USE_VT>
__global__ __launch_bounds__(256, 4)
void gemm_kernel(const float* __restrict__ A,
                 const unsigned char* __restrict__ Vt,
                 const float* __restrict__ Vf, float* __restrict__ out,
                 const unsigned* __restrict__ amax_bits) {
  float amax_a = fmaxf(__uint_as_float(amax_bits[0]), 1e-12f);
  float amax_v = fmaxf(__uint_as_float(amax_bits[1]), 1e-12f);
  float inv_a  = 448.0f / amax_a;
  float inv_v  = 448.0f / amax_v;
  float out_scale = (amax_a / 448.0f) * (amax_v / 448.0f);

  int bid  = blockIdx.x;
  int bh   = bid >> 5;                 // 0..31
  int t0   = (bid & 31) * 64;
  int b    = bh >> 4;                  // H_=16
  int h    = bh & 15;

  int wave = threadIdx.x >> 6;         // 0..3 -> rows [t0+16w, +16)
  int lane = threadIdx.x & 63;
  int lr   = lane & 15;                // A row-in-frag / B col / C col
  int kg   = lane >> 4;                // k-group (k = kg*8 + j)

  const float* arow =
      A + (size_t)bh * T_ * S_ + (size_t)(t0 + wave * 16 + lr) * S_;
  const unsigned char* vrow = Vt + (size_t)bh * D_ * S_ + (size_t)lr * S_;
  const float* vfb = Vf + (size_t)bh * S_ * D_;

  f32x4 acc[8];
  #pragma unroll
  for (int j = 0; j < 8; ++j) acc[j] = (f32x4)0.0f;

  for (int ks = 0; ks < S_ / 32; ++ks) {
    int kb = ks * 32 + kg * 8;

    // ---- B fragments: lane holds Vq[kb..kb+7][d = ni*16+lr] as 8 e4m3 bytes
    long bfrag[8];
    if (USE_VT) {
      #pragma unroll
      for (int ni = 0; ni < 8; ++ni)
        bfrag[ni] = *(const long*)(vrow + (size_t)ni * 16 * S_ + kb);
    } else {
      #pragma unroll
      for (int ni = 0; ni < 8; ++ni) {
        float f[8];
        #pragma unroll
        for (int j = 0; j < 8; ++j)
          f[j] = clamp448(vfb[(size_t)(kb + j) * D_ + ni * 16 + lr] * inv_v);
        bfrag[ni] = pack_fp8x8(f);
      }
    }

    // ---- A fragment: lane holds Aq[row][kb..kb+7], HW-quantized in-register
    f32x4 x0 = *(const f32x4*)(arow + kb);
    f32x4 x1 = *(const f32x4*)(arow + kb + 4);
    float f[8];
    #pragma unroll
    for (int j = 0; j < 4; ++j) {
      f[j]     = clamp448(x0[j] * inv_a);
      f[j + 4] = clamp448(x1[j] * inv_a);
    }
    long afrag = pack_fp8x8(f);

    #pragma unroll
    for (int ni = 0; ni < 8; ++ni)
      acc[ni] = __builtin_amdgcn_mfma_f32_16x16x32_fp8_fp8(
          afrag, bfrag[ni], acc[ni], 0, 0, 0);
  }

  // ---- epilogue: C/D layout col=lane&15, row=(lane>>4)*4+r  [guide §3, m89]
  // out[b][t][h][d], d = ni*16+lr, t = t0 + wave*16 + kg*4 + r
  float* ob = out + (size_t)b * T_ * H_ * D_ + (size_t)h * D_;
  int trow = t0 + wave * 16;
  #pragma unroll
  for (int ni = 0; ni < 8; ++ni) {
    int d = ni * 16 + lr;
    #pragma unroll
    for (int r = 0; r < 4; ++r) {
      int t = trow + kg * 4 + r;
      ob[(size_t)t * H_ * D_ + d] = acc[ni][r] * out_scale;
    }
  }
}

// ---------------------------------------------------------------------------
extern "C" void kernel_launch(void* const* d_in, const int* in_sizes, int n_in,
                              void* d_out, int out_size, void* d_ws, size_t ws_size,
                              hipStream_t stream) {
  const float* aw = (const float*)d_in[0];
  const float* v  = (const float*)d_in[1];
  float* out      = (float*)d_out;

  unsigned*      amax_bits = (unsigned*)d_ws;
  unsigned char* vt        = (unsigned char*)d_ws + 256;
  size_t vt_need = 256 + (size_t)B_ * H_ * D_ * S_;

  init_kernel<<<1, 64, 0, stream>>>(amax_bits);

  long n4a = (long)B_ * H_ * T_ * S_ / 4;
  long n4v = (long)B_ * H_ * S_ * D_ / 4;
  amax_kernel<<<2048, 256, 0, stream>>>(aw, n4a, amax_bits + 0);
  amax_kernel<<<256,  256, 0, stream>>>(v,  n4v, amax_bits + 1);

  if (ws_size >= vt_need) {
    quantv_kernel<<<32 * 64, 256, 0, stream>>>(v, vt, amax_bits);
    gemm_kernel<true><<<B_ * H_ * (T_ / 64), 256, 0, stream>>>(
        aw, vt, v, out, amax_bits);
  } else {
    gemm_kernel<false><<<B_ * H_ * (T_ / 64), 256, 0, stream>>>(
        aw, vt, v, out, amax_bits);
  }
}